// Round 9
// baseline (272.208 us; speedup 1.0000x reference)
//
#include <hip/hip_runtime.h>

#define N_POS 4096
#define NJ 4094     // N-2 valid sign-change positions
#define G 512       // row-groups (partial-count slices)
#define RPB 16      // rows per count-block = 8192 / G

typedef float f32x4 __attribute__((ext_vector_type(4)));  // nt-store-compatible

// ---------------------------------------------------------------------------
// Kernel 1: partial peak/valley counts — ZERO atomics, max occupancy.
// Grid: (4 position-chunks of 1024, G=512 row-groups) = 2048 blocks = 8/CU,
// 32 waves/CU (VGPR kept <= 64 by pinning the batch loop at 8 rows with
// unroll(1)). Each thread owns 4 consecutive positions; float4 + overlapping
// float2 loads register-staged per 8-row batch (~12 KB in flight per wave).
// Each block writes packed counts (pk | vl<<16) to its OWN slice
// partial[by][4096] with one uint4 store — no contention, no RMW. Garbage
// counts at j >= NJ are masked in kernel 2. Block (0,0) zeroes the two
// min/max keys (replaces the memset dispatch).
// ---------------------------------------------------------------------------
__global__ __launch_bounds__(256) void partial_kernel(
    const float* __restrict__ x,
    unsigned int* __restrict__ partial,
    unsigned int* __restrict__ mm)
{
    const int tid = threadIdx.x;
    const int j0  = blockIdx.x * 1024 + tid * 4;
    const size_t row0 = (size_t)blockIdx.y * RPB;

    if (blockIdx.x == 0 && blockIdx.y == 0 && tid == 0) {
        mm[0] = 0u;   // min key (atomicMax target in vec_kernel)
        mm[1] = 0u;   // max key
    }

    const float* base = x + row0 * N_POS + j0;
    const bool tail = (j0 + 4 >= N_POS);     // only j0 == 4092
    const int halo_off = tail ? -2 : 4;      // tail reads in-bounds garbage

    unsigned int pk0 = 0, pk1 = 0, pk2 = 0, pk3 = 0;
    unsigned int vl0 = 0, vl1 = 0, vl2 = 0, vl3 = 0;

    #pragma unroll 1
    for (int h = 0; h < RPB / 8; ++h) {
        float4 A[8];
        float2 B[8];
        const float* hb = base + (size_t)h * 8 * N_POS;
        #pragma unroll
        for (int r = 0; r < 8; ++r) {
            const float* rowp = hb + (size_t)r * N_POS;
            A[r] = *reinterpret_cast<const float4*>(rowp);
            B[r] = *reinterpret_cast<const float2*>(rowp + halo_off);
        }
        #pragma unroll
        for (int r = 0; r < 8; ++r) {
            const float4 a = A[r];
            const float n0 = B[r].x, n1 = B[r].y;
            float s;
            s = (a.z - a.y) - (a.y - a.x);
            pk0 += (s < 0.f); vl0 += (s > 0.f);
            s = (a.w - a.z) - (a.z - a.y);
            pk1 += (s < 0.f); vl1 += (s > 0.f);
            s = (n0 - a.w) - (a.w - a.z);
            pk2 += (s < 0.f); vl2 += (s > 0.f);
            s = (n1 - n0) - (n0 - a.w);
            pk3 += (s < 0.f); vl3 += (s > 0.f);
        }
    }

    uint4 o;
    o.x = pk0 | (vl0 << 16);
    o.y = pk1 | (vl1 << 16);
    o.z = pk2 | (vl2 << 16);
    o.w = pk3 | (vl3 << 16);
    *reinterpret_cast<uint4*>(&partial[(size_t)blockIdx.y * N_POS + j0]) = o;
}

// ---------------------------------------------------------------------------
// Kernel 2: group-sum + vec + global min/max. 16 blocks x 1024 threads.
// Phase 1: task (q = tid>>3, sub = tid&7) sums G/8 = 64 uint4 partial
// columns for quad q of the 512-wide halo window (jb = bx*256-128, quad-
// aligned). Per-field overflow safe: pk,vl <= RPB per partial word, so
// sub-sum <= 16*64 = 1024 and full sum <= 8192 < 2^16. Phase 2: tid<128
// combines 8 sub-sums, unpacks with NJ mask into s_pk/s_vl. Phase 3:
// tid<256 does the Gaussian conv (radius clamped to 124; for w=3 R=25;
// dropped terms < e^-64, negligible vs the 2e-2 threshold). Min/max via
// monotonic-uint atomicMax on mm (vec >= 0).
// ---------------------------------------------------------------------------
__global__ __launch_bounds__(1024) void vec_kernel(
    const unsigned int* __restrict__ partial,
    const float* __restrict__ log_pw,
    const float* __restrict__ log_vw,
    float* __restrict__ vec,
    unsigned int* __restrict__ mm)
{
    __shared__ uint4  s_red[128][8];
    __shared__ float  s_pk[512], s_vl[512];
    __shared__ float  s_gp[256], s_gv[256];   // dist = idx - 128
    __shared__ float  smn[4], smx[4];

    const int tid = threadIdx.x;
    const int jb  = blockIdx.x * 256 - 128;   // quad-aligned window base

    // Phase 1: partial group-sums (all 1024 threads)
    {
        const int q = tid >> 3, sub = tid & 7;
        const int jq = jb + q * 4;
        uint4 acc; acc.x = acc.y = acc.z = acc.w = 0;
        if (jq >= 0 && jq + 3 < N_POS) {
            const unsigned int* colp = partial + (size_t)(sub * (G / 8)) * N_POS + jq;
            #pragma unroll 4
            for (int g = 0; g < G / 8; ++g) {
                uint4 v = *reinterpret_cast<const uint4*>(colp + (size_t)g * N_POS);
                acc.x += v.x; acc.y += v.y; acc.z += v.z; acc.w += v.w;
            }
        }
        s_red[q][sub] = acc;
    }

    // Gaussian tables (threads 0..255)
    const float wp = __expf(log_pw[0]);
    const float wv = __expf(log_vw[0]);
    const float ip2 = 1.f / (wp * wp);
    const float iv2 = 1.f / (wv * wv);
    const int Rp = min(124, (int)ceilf(wp * 8.f) + 1);
    const int Rv = min(124, (int)ceilf(wv * 8.f) + 1);
    if (tid < 256) {
        float dd = (float)(tid - 128);
        s_gp[tid] = __expf(-dd * dd * ip2);
        s_gv[tid] = __expf(-dd * dd * iv2);
    }
    __syncthreads();

    // Phase 2: combine 8 sub-sums, unpack with NJ mask
    if (tid < 128) {
        uint4 a; a.x = a.y = a.z = a.w = 0;
        #pragma unroll
        for (int s = 0; s < 8; ++s) {
            uint4 v = s_red[tid][s];
            a.x += v.x; a.y += v.y; a.z += v.z; a.w += v.w;
        }
        const int jq = jb + tid * 4;
        unsigned int e[4] = {a.x, a.y, a.z, a.w};
        #pragma unroll
        for (int k = 0; k < 4; ++k) {
            int j = jq + k;
            unsigned int c = (j >= 0 && j < NJ) ? e[k] : 0u;
            s_pk[tid * 4 + k] = (float)(c & 0xFFFFu);
            s_vl[tid * 4 + k] = (float)(c >> 16);
        }
    }
    __syncthreads();

    // Phase 3: convolution + min/max (threads 0..255)
    if (tid < 256) {
        const int p = blockIdx.x * 256 + tid;
        float sum = 0.f;
        {   // peaks: centers c = j+1 in [1, NJ]
            int clo = max(1, p - Rp), chi = min(NJ, p + Rp);
            for (int c = clo; c <= chi; ++c)
                sum += s_pk[c - 1 - jb] * s_gp[p - c + 128];
        }
        {   // valleys
            int clo = max(1, p - Rv), chi = min(NJ, p + Rv);
            for (int c = clo; c <= chi; ++c)
                sum += s_vl[c - 1 - jb] * s_gv[p - c + 128];
        }
        vec[p] = sum;

        float mn = sum, mx = sum;
        for (int off = 32; off; off >>= 1) {
            mn = fminf(mn, __shfl_down(mn, off));
            mx = fmaxf(mx, __shfl_down(mx, off));
        }
        if ((tid & 63) == 0) { smn[tid >> 6] = mn; smx[tid >> 6] = mx; }
    }
    __syncthreads();
    if (tid == 0) {
        float mn = fminf(fminf(smn[0], smn[1]), fminf(smn[2], smn[3]));
        float mx = fmaxf(fmaxf(smx[0], smx[1]), fmaxf(smx[2], smx[3]));
        atomicMax(&mm[0], 0x7FFFFFFFu - __float_as_uint(mn));  // min key
        atomicMax(&mm[1], __float_as_uint(mx));                // max key
    }
}

// ---------------------------------------------------------------------------
// Kernel 3: broadcast + normalize. vec (16 KiB) is L1/L2-resident; write-
// bound at ~134 MB. Nontemporal stores skip L2 write-allocate; normalization
// fused (4 FMAs per float4 store, free against write BW).
// ---------------------------------------------------------------------------
__global__ __launch_bounds__(256) void bcast_kernel(
    const float4* __restrict__ vec4,
    const unsigned int* __restrict__ mm,
    f32x4* __restrict__ out4, int total4)
{
    const float mn  = __uint_as_float(0x7FFFFFFFu - mm[0]);
    const float mx  = __uint_as_float(mm[1]);
    const float inv = 1.f / (mx - mn + 1e-6f);

    int idx    = blockIdx.x * blockDim.x + threadIdx.x;
    int stride = gridDim.x * blockDim.x;
    for (int i = idx; i < total4; i += stride) {
        float4 v = vec4[i & 1023];   // N/4 = 1024 (power of two)
        f32x4 o;
        o.x = (v.x - mn) * inv;
        o.y = (v.y - mn) * inv;
        o.z = (v.z - mn) * inv;
        o.w = (v.w - mn) * inv;
        __builtin_nontemporal_store(o, &out4[i]);
    }
}

extern "C" void kernel_launch(void* const* d_in, const int* in_sizes, int n_in,
                              void* d_out, int out_size, void* d_ws, size_t ws_size,
                              hipStream_t stream) {
    const float* x   = (const float*)d_in[0];
    const float* lpw = (const float*)d_in[1];
    const float* lvw = (const float*)d_in[2];

    float* vec = (float*)d_ws;                        // [0..4095], 16B aligned
    unsigned int* mm = (unsigned int*)d_ws + 4096;    // [4096..4097] keys
    unsigned int* partial = (unsigned int*)d_ws + 4352;  // 16B aligned, 8 MB

    // no memset: partial is fully overwritten; mm zeroed by partial_kernel

    dim3 g1(4, G);
    partial_kernel<<<g1, 256, 0, stream>>>(x, partial, mm);
    vec_kernel<<<16, 1024, 0, stream>>>(partial, lpw, lvw, vec, mm);
    bcast_kernel<<<2048, 256, 0, stream>>>((const float4*)vec, mm,
                                           (f32x4*)d_out, out_size / 4);
}

// Round 12
// 257.576 us; speedup vs baseline: 1.0568x; 1.0568x over previous
//
#include <hip/hip_runtime.h>

#define N_POS 4096
#define NJ 4094     // N-2 valid sign-change positions
#define G 256       // row-groups (partial-count slices)
#define RPB 32      // rows per count-block = 8192 / G

typedef float f32x4 __attribute__((ext_vector_type(4)));  // nt-store-compatible

// ---------------------------------------------------------------------------
// Kernel 1: partial peak/valley counts — zero atomics, copy-shaped loads.
// Grid: (4 position-chunks of 1024, G=256 row-groups) = 1024 blocks = 4/CU,
// 16 waves/CU. Each thread owns 4 consecutive positions; ONE float4 load per
// 16 B of payload (register-staged 8 rows/batch). The 2-float halo comes
// from __shfl_down (LDS pipe, no VMEM); only lane 63 of each wave issues an
// exec-masked float2 load (1 cache-line request per wave-row vs 8 for the
// old all-lanes float2). Tail thread (j0 == 4092) clamps its halo load
// in-bounds; the garbage only feeds k >= NJ outputs, masked in kernel 2.
// Each block writes packed counts (pk | vl<<16) to its own slice
// partial[by][4096] with one uint4 store. Block (0,0) zeroes the min/max
// keys (replaces the memset dispatch).
// ---------------------------------------------------------------------------
__global__ __launch_bounds__(256) void partial_kernel(
    const float* __restrict__ x,
    unsigned int* __restrict__ partial,
    unsigned int* __restrict__ mm)
{
    const int tid  = threadIdx.x;
    const int lane = tid & 63;
    const int j0   = blockIdx.x * 1024 + tid * 4;
    const size_t row0 = (size_t)blockIdx.y * RPB;

    if (blockIdx.x == 0 && blockIdx.y == 0 && tid == 0) {
        mm[0] = 0u;   // min key (atomicMax target in vec_kernel)
        mm[1] = 0u;   // max key
    }

    const float* base = x + row0 * N_POS + j0;
    const bool tail = (j0 + 4 >= N_POS);     // only j0 == 4092
    const int halo_off = tail ? -2 : 4;      // tail reads in-bounds garbage

    unsigned int pk0 = 0, pk1 = 0, pk2 = 0, pk3 = 0;
    unsigned int vl0 = 0, vl1 = 0, vl2 = 0, vl3 = 0;

    #pragma unroll 1
    for (int h = 0; h < RPB / 8; ++h) {
        float4 A[8];
        float2 B[8];
        const float* hb = base + (size_t)h * 8 * N_POS;
        #pragma unroll
        for (int r = 0; r < 8; ++r) {
            const float* rowp = hb + (size_t)r * N_POS;
            A[r] = *reinterpret_cast<const float4*>(rowp);
            if (lane == 63)   // exec-masked: 1 line-request per wave-row
                B[r] = *reinterpret_cast<const float2*>(rowp + halo_off);
        }
        #pragma unroll
        for (int r = 0; r < 8; ++r) {
            const float4 a = A[r];
            float n0 = __shfl_down(a.x, 1);
            float n1 = __shfl_down(a.y, 1);
            if (lane == 63) { n0 = B[r].x; n1 = B[r].y; }
            float s;
            s = (a.z - a.y) - (a.y - a.x);
            pk0 += (s < 0.f); vl0 += (s > 0.f);
            s = (a.w - a.z) - (a.z - a.y);
            pk1 += (s < 0.f); vl1 += (s > 0.f);
            s = (n0 - a.w) - (a.w - a.z);
            pk2 += (s < 0.f); vl2 += (s > 0.f);
            s = (n1 - n0) - (n0 - a.w);
            pk3 += (s < 0.f); vl3 += (s > 0.f);
        }
    }

    uint4 o;
    o.x = pk0 | (vl0 << 16);
    o.y = pk1 | (vl1 << 16);
    o.z = pk2 | (vl2 << 16);
    o.w = pk3 | (vl3 << 16);
    *reinterpret_cast<uint4*>(&partial[(size_t)blockIdx.y * N_POS + j0]) = o;
}

// ---------------------------------------------------------------------------
// Kernel 2: group-sum + vec + global min/max. 16 blocks x 1024 threads.
// Phase 1: task (q = tid>>3, sub = tid&7) sums G/8 = 32 uint4 partial
// columns for quad q of the 512-wide halo window (jb = bx*256-128, quad-
// aligned). Overflow safe: per-field sub-sum <= 32*32 = 1024 and full sum
// <= 8192 < 2^16. Phase 2: tid<128 combines 8 sub-sums, unpacks with NJ
// mask into s_pk/s_vl. Phase 3: tid<256 does the Gaussian conv (radius
// clamped to 124; for w=3 R=25; dropped terms < e^-64, negligible vs the
// 2e-2 threshold). Min/max via monotonic-uint atomicMax on mm (vec >= 0).
// ---------------------------------------------------------------------------
__global__ __launch_bounds__(1024) void vec_kernel(
    const unsigned int* __restrict__ partial,
    const float* __restrict__ log_pw,
    const float* __restrict__ log_vw,
    float* __restrict__ vec,
    unsigned int* __restrict__ mm)
{
    __shared__ uint4  s_red[128][8];
    __shared__ float  s_pk[512], s_vl[512];
    __shared__ float  s_gp[256], s_gv[256];   // dist = idx - 128
    __shared__ float  smn[4], smx[4];

    const int tid = threadIdx.x;
    const int jb  = blockIdx.x * 256 - 128;   // quad-aligned window base

    // Phase 1: partial group-sums (all 1024 threads)
    {
        const int q = tid >> 3, sub = tid & 7;
        const int jq = jb + q * 4;
        uint4 acc; acc.x = acc.y = acc.z = acc.w = 0;
        if (jq >= 0 && jq + 3 < N_POS) {
            const unsigned int* colp = partial + (size_t)(sub * (G / 8)) * N_POS + jq;
            #pragma unroll 4
            for (int g = 0; g < G / 8; ++g) {
                uint4 v = *reinterpret_cast<const uint4*>(colp + (size_t)g * N_POS);
                acc.x += v.x; acc.y += v.y; acc.z += v.z; acc.w += v.w;
            }
        }
        s_red[q][sub] = acc;
    }

    // Gaussian tables (threads 0..255)
    const float wp = __expf(log_pw[0]);
    const float wv = __expf(log_vw[0]);
    const float ip2 = 1.f / (wp * wp);
    const float iv2 = 1.f / (wv * wv);
    const int Rp = min(124, (int)ceilf(wp * 8.f) + 1);
    const int Rv = min(124, (int)ceilf(wv * 8.f) + 1);
    if (tid < 256) {
        float dd = (float)(tid - 128);
        s_gp[tid] = __expf(-dd * dd * ip2);
        s_gv[tid] = __expf(-dd * dd * iv2);
    }
    __syncthreads();

    // Phase 2: combine 8 sub-sums, unpack with NJ mask
    if (tid < 128) {
        uint4 a; a.x = a.y = a.z = a.w = 0;
        #pragma unroll
        for (int s = 0; s < 8; ++s) {
            uint4 v = s_red[tid][s];
            a.x += v.x; a.y += v.y; a.z += v.z; a.w += v.w;
        }
        const int jq = jb + tid * 4;
        unsigned int e[4] = {a.x, a.y, a.z, a.w};
        #pragma unroll
        for (int k = 0; k < 4; ++k) {
            int j = jq + k;
            unsigned int c = (j >= 0 && j < NJ) ? e[k] : 0u;
            s_pk[tid * 4 + k] = (float)(c & 0xFFFFu);
            s_vl[tid * 4 + k] = (float)(c >> 16);
        }
    }
    __syncthreads();

    // Phase 3: convolution + min/max (threads 0..255)
    if (tid < 256) {
        const int p = blockIdx.x * 256 + tid;
        float sum = 0.f;
        {   // peaks: centers c = j+1 in [1, NJ]
            int clo = max(1, p - Rp), chi = min(NJ, p + Rp);
            for (int c = clo; c <= chi; ++c)
                sum += s_pk[c - 1 - jb] * s_gp[p - c + 128];
        }
        {   // valleys
            int clo = max(1, p - Rv), chi = min(NJ, p + Rv);
            for (int c = clo; c <= chi; ++c)
                sum += s_vl[c - 1 - jb] * s_gv[p - c + 128];
        }
        vec[p] = sum;

        float mn = sum, mx = sum;
        for (int off = 32; off; off >>= 1) {
            mn = fminf(mn, __shfl_down(mn, off));
            mx = fmaxf(mx, __shfl_down(mx, off));
        }
        if ((tid & 63) == 0) { smn[tid >> 6] = mn; smx[tid >> 6] = mx; }
    }
    __syncthreads();
    if (tid == 0) {
        float mn = fminf(fminf(smn[0], smn[1]), fminf(smn[2], smn[3]));
        float mx = fmaxf(fmaxf(smx[0], smx[1]), fmaxf(smx[2], smx[3]));
        atomicMax(&mm[0], 0x7FFFFFFFu - __float_as_uint(mn));  // min key
        atomicMax(&mm[1], __float_as_uint(mx));                // max key
    }
}

// ---------------------------------------------------------------------------
// Kernel 3: broadcast + normalize. vec (16 KiB) is L1/L2-resident; write-
// bound at ~134 MB. Nontemporal stores skip L2 write-allocate; normalization
// fused (4 FMAs per float4 store, free against write BW).
// ---------------------------------------------------------------------------
__global__ __launch_bounds__(256) void bcast_kernel(
    const float4* __restrict__ vec4,
    const unsigned int* __restrict__ mm,
    f32x4* __restrict__ out4, int total4)
{
    const float mn  = __uint_as_float(0x7FFFFFFFu - mm[0]);
    const float mx  = __uint_as_float(mm[1]);
    const float inv = 1.f / (mx - mn + 1e-6f);

    int idx    = blockIdx.x * blockDim.x + threadIdx.x;
    int stride = gridDim.x * blockDim.x;
    for (int i = idx; i < total4; i += stride) {
        float4 v = vec4[i & 1023];   // N/4 = 1024 (power of two)
        f32x4 o;
        o.x = (v.x - mn) * inv;
        o.y = (v.y - mn) * inv;
        o.z = (v.z - mn) * inv;
        o.w = (v.w - mn) * inv;
        __builtin_nontemporal_store(o, &out4[i]);
    }
}

extern "C" void kernel_launch(void* const* d_in, const int* in_sizes, int n_in,
                              void* d_out, int out_size, void* d_ws, size_t ws_size,
                              hipStream_t stream) {
    const float* x   = (const float*)d_in[0];
    const float* lpw = (const float*)d_in[1];
    const float* lvw = (const float*)d_in[2];

    float* vec = (float*)d_ws;                        // [0..4095], 16B aligned
    unsigned int* mm = (unsigned int*)d_ws + 4096;    // [4096..4097] keys
    unsigned int* partial = (unsigned int*)d_ws + 4352;  // 16B aligned, 4 MB

    // no memset: partial is fully overwritten; mm zeroed by partial_kernel

    dim3 g1(4, G);
    partial_kernel<<<g1, 256, 0, stream>>>(x, partial, mm);
    vec_kernel<<<16, 1024, 0, stream>>>(partial, lpw, lvw, vec, mm);
    bcast_kernel<<<2048, 256, 0, stream>>>((const float4*)vec, mm,
                                           (f32x4*)d_out, out_size / 4);
}